// Round 31
// baseline (350.665 us; speedup 1.0000x reference)
//
#include <hip/hip_runtime.h>
#include <hip/hip_fp16.h>
#include <math.h>

// Problem constants (from reference)
constexpr int N_NODES = 50000;
constexpr int N_EDGES = 1600000;
constexpr int HDIM    = 64;
constexpr int NLAYER  = 5;
constexpr int NBASIS  = 8;
constexpr int TLUT    = 128;           // radial LUT entries (7-bit index)
constexpr float CUT_R = 5.0f;
constexpr float PI_F  = 3.14159265358979f;

// binned scatter: buckets of 256 nodes (r >> 8)
constexpr int NBKT = 196;
constexpr int BCAP = 9216;             // mean 8192 + ~11 sigma
constexpr int TILE = 2048;
constexpr int NBLK_EMBED = 3125;       // (N_NODES*16)/256  (4 channels/thread)
constexpr int AGG_BLOCKS = 2048;       // 8 blocks/CU, grid-stride over nodes
constexpr int LP = 72;                 // LUT LDS row pitch in ushorts (144B, 16B-aligned)

typedef __attribute__((ext_vector_type(8))) short short8;   // 8 bf16 (4 VGPRs)
typedef __attribute__((ext_vector_type(4))) float f32x4;    // MFMA acc
#define MFMA16 __builtin_amdgcn_mfma_f32_16x16x32_bf16

__device__ __forceinline__ float siluf(float x) { return x / (1.0f + __expf(-x)); }

// round-to-nearest-even f32 -> bf16 bits
__device__ __forceinline__ unsigned int f2bf(float x) {
    unsigned int b = __float_as_uint(x);
    return (b + 0x7fffu + ((b >> 16) & 1u)) >> 16;
}
__device__ __forceinline__ float bf_lo(unsigned int u) { return __uint_as_float(u << 16); }

// f32 -> fp8 e5m2 (RTNE via fp16 truncation with rounding)
__device__ __forceinline__ unsigned int f2e5(float x) {
    unsigned short b = __half_as_ushort(__float2half(x));
    return ((unsigned int)b + 0x7Fu + ((b >> 8) & 1u)) >> 8;
}

// uint <-> __half2 bit casts
__device__ __forceinline__ __half2 u2h2(unsigned int u) {
    union { unsigned int u; __half2 h; } x; x.u = u; return x.h;
}
__device__ __forceinline__ unsigned int h2u(__half2 h) {
    union { __half2 h; unsigned int u; } x; x.h = h; return x.u;
}

// block-wide exclusive scan of 256 values: wave shuffle scans + LDS combine.
__device__ __forceinline__ int blockScan256Excl(int cv, int tid, int* wtot) {
    int v = cv;
    int lane = tid & 63;
    #pragma unroll
    for (int off = 1; off < 64; off <<= 1) {
        int t = __shfl_up(v, off, 64);
        if (lane >= off) v += t;
    }
    if (lane == 63) wtot[tid >> 6] = v;
    __syncthreads();
    int pre = 0;
    #pragma unroll
    for (int w = 0; w < 4; ++w)
        if (w < (tid >> 6)) pre += wtot[w];
    __syncthreads();
    return v + pre - cv;                 // exclusive
}

// ---------------- setup kernels ----------------

// fused: node embedding (vectorized, 4 ch/thread) + per-edge record precompute
__global__ void k_init(const int* __restrict__ an, const float* __restrict__ embed,
                       unsigned short* __restrict__ featsbf,
                       unsigned char* __restrict__ featsf8,
                       const int* __restrict__ row, const int* __restrict__ col,
                       const float* __restrict__ pos,
                       unsigned int* __restrict__ rec4, unsigned char* __restrict__ bkt) {
    int b = blockIdx.x;
    if (b < NBLK_EMBED) {
        int i = b * 256 + threadIdx.x;          // 0 .. N_NODES*16-1
        int node = i >> 4, h4 = (i & 15) << 2;
        float4 v = *(const float4*)&embed[an[node] * HDIM + h4];
        ushort4 ub;
        ub.x = (unsigned short)f2bf(v.x); ub.y = (unsigned short)f2bf(v.y);
        ub.z = (unsigned short)f2bf(v.z); ub.w = (unsigned short)f2bf(v.w);
        *(ushort4*)&featsbf[(size_t)node * 64 + h4] = ub;
        uchar4 uc;
        uc.x = (unsigned char)f2e5(v.x); uc.y = (unsigned char)f2e5(v.y);
        uc.z = (unsigned char)f2e5(v.z); uc.w = (unsigned char)f2e5(v.w);
        *(uchar4*)&featsf8[(size_t)node * 64 + h4] = uc;
    } else {
        int e = (b - NBLK_EMBED) * 256 + threadIdx.x;
        if (e >= N_EDGES) return;
        int r = row[e], c = col[e];
        float dx = pos[c * 3 + 0] - pos[r * 3 + 0];
        float dy = pos[c * 3 + 1] - pos[r * 3 + 1];
        float dz = pos[c * 3 + 2] - pos[r * 3 + 2];
        float len = sqrtf(dx * dx + dy * dy + dz * dz);
        float t = len * ((float)(TLUT - 1) / CUT_R);
        t = fminf(t, (float)(TLUT - 1));
        unsigned int nn = (unsigned int)(t + 0.5f);
        if (nn > TLUT - 1) nn = TLUT - 1;
        rec4[e] = ((unsigned int)c << 16) | (nn << 8) | ((unsigned int)r & 255u);
        bkt[e]  = (unsigned char)(r >> 8);
    }
}

// pass A: pure LDS sort of precomputed records into bucket runs
__global__ __launch_bounds__(256) void k_binA(const unsigned int* __restrict__ rec4,
                                              const unsigned char* __restrict__ bkt,
                                              int* __restrict__ btail,
                                              unsigned int* __restrict__ binned) {
    __shared__ unsigned int ent[TILE];
    __shared__ short bb[TILE];
    __shared__ unsigned int sorted[TILE];
    __shared__ short sortedB[TILE];
    __shared__ int cnt[256], cnt2[256], base[256], gbase[256];
    __shared__ int wtot[4];
    const int tid = threadIdx.x;
    const int t0  = blockIdx.x * TILE;
    const int nv  = min(TILE, N_EDGES - t0);

    cnt[tid] = 0;
    __syncthreads();

    #pragma unroll
    for (int i = 0; i < TILE / 256; ++i) {
        int idx = i * 256 + tid;
        if (idx < nv) {
            ent[idx] = rec4[t0 + idx];
            int b = bkt[t0 + idx];
            bb[idx] = (short)b;
            atomicAdd(&cnt[b], 1);
        }
    }
    __syncthreads();
    int cv = cnt[tid];
    int excl = blockScan256Excl(cv, tid, wtot);
    base[tid] = excl;
    if (tid < NBKT && cv > 0) gbase[tid] = atomicAdd(&btail[tid], cv);
    cnt2[tid] = excl;
    __syncthreads();
    #pragma unroll
    for (int i = 0; i < TILE / 256; ++i) {
        int idx = i * 256 + tid;
        if (idx < nv) {
            int b = bb[idx];
            int p = atomicAdd(&cnt2[b], 1);
            sorted[p]  = ent[idx];
            sortedB[p] = (short)b;
        }
    }
    __syncthreads();
    for (int s = tid; s < nv; s += 256) {
        int b = sortedB[s];
        binned[(size_t)b * BCAP + gbase[b] + (s - base[b])] = sorted[s];
    }
}

// pass B: one block per 256-node bucket. Inline prefix over btail -> LDS
// histogram -> wave scan -> starts -> scatter erec via LDS cursors.
__global__ __launch_bounds__(256) void k_binB(const unsigned int* __restrict__ binned,
                                              const int* __restrict__ btail,
                                              int* __restrict__ starts,
                                              unsigned int* __restrict__ erec) {
    __shared__ int hist[256];
    __shared__ int cur[256];
    __shared__ int red[256];
    __shared__ int wtot[4];
    const int b = blockIdx.x;
    const int node0 = b << 8;
    const int t = threadIdx.x;
    int part = 0;
    for (int i = t; i < b; i += 256) part += btail[i];
    red[t] = part;
    hist[t] = 0;
    __syncthreads();
    for (int off = 128; off > 0; off >>= 1) {
        if (t < off) red[t] += red[t + off];
        __syncthreads();
    }
    const int bb0 = red[0];
    const int cnt = btail[b];
    const unsigned int* src = binned + (size_t)b * BCAP;
    for (int s = t; s < cnt; s += 256)
        atomicAdd(&hist[src[s] & 255u], 1);
    __syncthreads();
    int h = hist[t];
    int excl = bb0 + blockScan256Excl(h, t, wtot);
    int n = node0 + t;
    if (n < N_NODES) starts[n] = excl;
    if (b == 0 && t == 0) starts[N_NODES] = N_EDGES;
    cur[t] = excl;
    __syncthreads();
    for (int s = t; s < cnt; s += 256) {
        unsigned int p = src[s];
        int pp = atomicAdd(&cur[p & 255u], 1);
        erec[pp] = p;
    }
}

// fused: W2s/Wsp + biases b2s/bsp
__global__ void k_prep(const float* __restrict__ rad_w2, const float* __restrict__ self_w,
                       const float* __restrict__ proj_w,
                       const float* __restrict__ rad_b2, const float* __restrict__ self_b,
                       const float* __restrict__ proj_b,
                       float* __restrict__ W2s, float* __restrict__ Wsp,
                       float* __restrict__ b2s, float* __restrict__ bsp) {
    int i = blockIdx.x * blockDim.x + threadIdx.x;
    if (i < NLAYER * HDIM * HDIM) {
        int l = i / (HDIM * HDIM); int rem = i % (HDIM * HDIM);
        int k = rem / HDIM; int h = rem % HDIM;
        const float* w = rad_w2 + ((size_t)l * HDIM + k) * (HDIM * 3) + h * 3;
        W2s[i] = w[0] + w[1] + w[2];
        const float* sw = self_w + ((size_t)l * HDIM + k) * HDIM;
        const float* pw = proj_w + (size_t)l * 2 * HDIM * HDIM;
        float acc = 0.f;
        for (int m = 0; m < HDIM; ++m) acc += sw[m] * pw[m * HDIM + h];
        Wsp[i] = acc;
    } else {
        int i2 = i - NLAYER * HDIM * HDIM;
        if (i2 >= NLAYER * HDIM) return;
        int l = i2 / HDIM, h = i2 % HDIM;
        const float* rb2 = rad_b2 + l * HDIM * 3 + h * 3;
        b2s[i2] = rb2[0] + rb2[1] + rb2[2];
        float acc = proj_b[l * HDIM + h];
        const float* pw = proj_w + (size_t)l * 2 * HDIM * HDIM;
        const float* sb = self_b + l * HDIM;
        for (int m = 0; m < HDIM; ++m) acc += sb[m] * pw[m * HDIM + h];
        bsp[i2] = acc;
    }
}

// fused: bf16 transposed weights + readout weights
__global__ void k_wtr(const float* __restrict__ Wsp, const float* __restrict__ proj_w,
                      const float* __restrict__ mlp_w1, const float* __restrict__ mlp_w2,
                      const float* __restrict__ ro_w1, const float* __restrict__ ro_w2,
                      unsigned short* __restrict__ WspT, unsigned short* __restrict__ PbT,
                      unsigned short* __restrict__ W1T, unsigned short* __restrict__ W2T,
                      unsigned short* __restrict__ Ro1T, unsigned short* __restrict__ Ro2T) {
    int i = blockIdx.x * blockDim.x + threadIdx.x;
    if (i < NLAYER * 24576) {
        int l = i / 24576, off = i % 24576;
        if (off < 4096) {
            int n = off >> 6, k = off & 63;
            WspT[(size_t)l * 4096 + off] = (unsigned short)f2bf(Wsp[(size_t)l * 4096 + k * 64 + n]);
        } else if (off < 8192) {
            int o = off - 4096; int n = o >> 6, k = o & 63;
            PbT[(size_t)l * 4096 + o] =
                (unsigned short)f2bf(proj_w[(size_t)l * 8192 + (64 + k) * 64 + n]);
        } else if (off < 16384) {
            int o = off - 8192; int n = o >> 6, k = o & 63;
            W1T[(size_t)l * 8192 + o] = (unsigned short)f2bf(mlp_w1[(size_t)l * 8192 + k * 128 + n]);
        } else {
            int o = off - 16384; int n = o >> 7, k = o & 127;
            W2T[(size_t)l * 8192 + o] = (unsigned short)f2bf(mlp_w2[(size_t)l * 8192 + k * 64 + n]);
        }
    } else {
        int i2 = i - NLAYER * 24576;
        if (i2 >= 6144) return;
        if (i2 < 4096) {
            int n = i2 >> 6, k = i2 & 63;
            Ro1T[i2] = (unsigned short)f2bf(ro_w1[k * 64 + n]);
        } else {
            int o = i2 - 4096; int n = o >> 6, k = o & 63;
            Ro2T[o] = (unsigned short)f2bf(ro_w2[k * 32 + n]);
        }
    }
}

// radial LUT -> fp16 directly, channel positions pair-permuted for hfma2:
// within each 8-channel group, memory order is ch {0,2,1,3,4,6,5,7}.
__global__ void k_lut(const float* __restrict__ widths, const float* __restrict__ rad_w1,
                      const float* __restrict__ rad_b1, const float* __restrict__ W2s,
                      const float* __restrict__ b2s, unsigned short* __restrict__ lutH) {
    int bid = blockIdx.x;                 // l*TLUT + t
    int l = bid / TLUT, t = bid % TLUT;
    int h = threadIdx.x;                  // 64 threads
    __shared__ float h1s[HDIM];
    float len = (float)t * (CUT_R / (float)(TLUT - 1));
    float cut = 0.0f;
    if (len < CUT_R) cut = 0.5f * (cosf(len * (PI_F / CUT_R)) + 1.0f);
    float acc = rad_b1[l * HDIM + h];
    for (int b = 0; b < NBASIS; ++b) {
        float wb = fmaxf(widths[b], 0.1f);
        float center = (float)b * (CUT_R / (float)(NBASIS - 1));
        float d = (len - center) / wb;
        float rbf = __expf(-0.5f * d * d) * cut;
        acc += rbf * rad_w1[(l * NBASIS + b) * HDIM + h];
    }
    h1s[h] = siluf(acc);
    __syncthreads();
    float o = b2s[l * HDIM + h];
    const float* w2 = W2s + (size_t)l * HDIM * HDIM;
    for (int k = 0; k < HDIM; ++k) o += h1s[k] * w2[k * HDIM + h];
    int m = h & 7;
    int pos = (h & ~7) | (m & 4) | ((m & 1) << 1) | ((m >> 1) & 1);
    lutH[(size_t)bid * HDIM + pos] = __half_as_ushort(__float2half(o));
}

// ---------------- per-layer kernels ----------------

// grid-stride, 8 blocks/CU. LUT staged to LDS (144B row pitch) -> per-edge LUT
// reads hit the LDS pipe, leaving L1 entirely to the random feats gather.
__global__ __launch_bounds__(256) void k_agg(const uint2* __restrict__ featsf8_2,
                                             const uint4* __restrict__ lutH4_l,
                                             const int* __restrict__ starts,
                                             const unsigned int* __restrict__ erec,
                                             uint4* __restrict__ aggbf4) {
    __shared__ unsigned short lutS[TLUT * LP];     // 18432 B
    const int tid  = threadIdx.x;
    const int lane = tid & 63;
    const int slot = lane >> 3;    // 0..7
    const int j    = lane & 7;     // channel octet

    // stage LUT: 128 rows x 8 uint4, coalesced
    #pragma unroll
    for (int i = 0; i < 4; ++i) {
        int g = i * 256 + tid;     // 0..1023
        int row = g >> 3, q = g & 7;
        *(uint4*)&lutS[row * LP + q * 8] = lutH4_l[g];
    }
    __syncthreads();

    for (int wid = blockIdx.x * 4 + (tid >> 6); wid < N_NODES; wid += AGG_BLOCKS * 4) {
        int e0 = starts[wid], e1 = starts[wid + 1];
        __half2 a02 = u2h2(0u), a13 = u2h2(0u), a46 = u2h2(0u), a57 = u2h2(0u);
        #pragma unroll 2
        for (int e = e0 + slot; e < e1; e += 8) {
            unsigned int rec = erec[e];
            int c  = rec >> 16;
            int i0 = (rec >> 8) & 255;
            uint4 qw = *(const uint4*)&lutS[i0 * LP + j * 8];
            uint2 fb = featsf8_2[(size_t)c * 8 + j];
            a02 = __hfma2(u2h2((fb.x << 8) & 0xFF00FF00u), u2h2(qw.x), a02);
            a13 = __hfma2(u2h2(fb.x & 0xFF00FF00u),        u2h2(qw.y), a13);
            a46 = __hfma2(u2h2((fb.y << 8) & 0xFF00FF00u), u2h2(qw.z), a46);
            a57 = __hfma2(u2h2(fb.y & 0xFF00FF00u),        u2h2(qw.w), a57);
        }
        #pragma unroll
        for (int off = 8; off < 64; off <<= 1) {
            a02 = __hadd2(a02, u2h2((unsigned int)__shfl_xor((int)h2u(a02), off, 64)));
            a13 = __hadd2(a13, u2h2((unsigned int)__shfl_xor((int)h2u(a13), off, 64)));
            a46 = __hadd2(a46, u2h2((unsigned int)__shfl_xor((int)h2u(a46), off, 64)));
            a57 = __hadd2(a57, u2h2((unsigned int)__shfl_xor((int)h2u(a57), off, 64)));
        }
        if (slot == 0) {
            float c0 = __low2float(a02), c2 = __high2float(a02);
            float c1 = __low2float(a13), c3 = __high2float(a13);
            float c4 = __low2float(a46), c6 = __high2float(a46);
            float c5 = __low2float(a57), c7 = __high2float(a57);
            uint4 o;
            o.x = f2bf(c0) | (f2bf(c1) << 16);
            o.y = f2bf(c2) | (f2bf(c3) << 16);
            o.z = f2bf(c4) | (f2bf(c5) << 16);
            o.w = f2bf(c6) | (f2bf(c7) << 16);
            aggbf4[(size_t)wid * 8 + j] = o;
        }
    }
}

// k_node (MFMA): 64 nodes/block, 4 waves, barrier-free in the layer path.
// Input A-operands (x, agg) read DIRECTLY from global as 16B fragments
// (wave touches 16 rows x one 64B line per load -> fully coalesced).
// LDS P/Q/S hold only intra-wave intermediates (conv-out, m1) in per-wave
// 16-row bands. FINAL keeps one barrier before the cross-wave sred.
constexpr int BP = 72;                     // bf16 LDS row pitch (144B, 16B-aligned)
template <bool FINAL>
__global__ __launch_bounds__(256) void k_node(
        unsigned short* __restrict__ featsbf,
        unsigned char* __restrict__ featsf8,
        const unsigned short* __restrict__ aggbf,
        const unsigned short* __restrict__ WspT_l, const unsigned short* __restrict__ PbT_l,
        const unsigned short* __restrict__ W1T_l, const unsigned short* __restrict__ W2T_l,
        const float* __restrict__ bsp_l,
        const float* __restrict__ mlp_b1_l, const float* __restrict__ mlp_b2_l,
        const float* __restrict__ ln_g_l, const float* __restrict__ ln_b_l,
        const int* __restrict__ an,
        const unsigned short* __restrict__ Ro1T, const unsigned short* __restrict__ Ro2T,
        const float* __restrict__ ro_b1, const float* __restrict__ ro_b2,
        const float* __restrict__ ro_w3, const float* __restrict__ ro_b3,
        const float* __restrict__ atomic_e, float* __restrict__ blockpart) {
    __shared__ unsigned short P[64 * BP];   // conv-out -> LN out
    __shared__ unsigned short Q[64 * BP];   // m1_lo -> (FINAL: h1)
    __shared__ unsigned short S[64 * BP];   // m1_hi -> f8 band tile / sred
    const int tid  = threadIdx.x;
    const int lane = tid & 63;
    const int wib  = tid >> 6;
    const int mt   = __builtin_amdgcn_readfirstlane(wib);
    const int nb0  = blockIdx.x * 64;
    const int colL = lane & 15;
    const int kgrp = lane >> 4;

    const unsigned short* gX = featsbf + (size_t)nb0 * 64;
    const unsigned short* gA = aggbf  + (size_t)nb0 * 64;

    // snapshot residual x (C-layout positions) direct from global
    float xres[4][4];                       // [nt][j]
    #pragma unroll
    for (int j = 0; j < 4; ++j)
        #pragma unroll
        for (int nt = 0; nt < 4; ++nt)
            xres[nt][j] = bf_lo(gX[(mt * 16 + kgrp * 4 + j) * 64 + nt * 16 + colL]);

    // ---- conv = x@Wsp + a@Pb + bsp (A-operands direct from global) ----
    f32x4 acc[4];
    #pragma unroll
    for (int nt = 0; nt < 4; ++nt) {
        float b = bsp_l[nt * 16 + colL];
        acc[nt][0] = b; acc[nt][1] = b; acc[nt][2] = b; acc[nt][3] = b;
    }
    #pragma unroll
    for (int kb = 0; kb < 2; ++kb) {
        short8 ax = *(const short8*)&gX[(mt * 16 + colL) * 64 + kb * 32 + kgrp * 8];
        short8 aa = *(const short8*)&gA[(mt * 16 + colL) * 64 + kb * 32 + kgrp * 8];
        #pragma unroll
        for (int nt = 0; nt < 4; ++nt) {
            short8 bw = *(const short8*)&WspT_l[(nt * 16 + colL) * 64 + kb * 32 + kgrp * 8];
            acc[nt] = MFMA16(ax, bw, acc[nt], 0, 0, 0);
            short8 bp = *(const short8*)&PbT_l[(nt * 16 + colL) * 64 + kb * 32 + kgrp * 8];
            acc[nt] = MFMA16(aa, bp, acc[nt], 0, 0, 0);
        }
    }
    #pragma unroll
    for (int nt = 0; nt < 4; ++nt)
        #pragma unroll
        for (int j = 0; j < 4; ++j)
            P[(mt * 16 + kgrp * 4 + j) * BP + nt * 16 + colL] = (unsigned short)f2bf(acc[nt][j]);

    // ---- m1 = silu(conv@W1 + b1), 128 wide ----
    {
        f32x4 m[8];
        #pragma unroll
        for (int nt = 0; nt < 8; ++nt) {
            float b = mlp_b1_l[nt * 16 + colL];
            m[nt][0] = b; m[nt][1] = b; m[nt][2] = b; m[nt][3] = b;
        }
        #pragma unroll
        for (int kb = 0; kb < 2; ++kb) {
            short8 ac = *(const short8*)&P[(mt * 16 + colL) * BP + kb * 32 + kgrp * 8];
            #pragma unroll
            for (int nt = 0; nt < 8; ++nt) {
                short8 bw = *(const short8*)&W1T_l[(nt * 16 + colL) * 64 + kb * 32 + kgrp * 8];
                m[nt] = MFMA16(ac, bw, m[nt], 0, 0, 0);
            }
        }
        #pragma unroll
        for (int nt = 0; nt < 4; ++nt)
            #pragma unroll
            for (int j = 0; j < 4; ++j)
                Q[(mt * 16 + kgrp * 4 + j) * BP + nt * 16 + colL] =
                    (unsigned short)f2bf(siluf(m[nt][j]));
        #pragma unroll
        for (int nt = 4; nt < 8; ++nt)
            #pragma unroll
            for (int j = 0; j < 4; ++j)
                S[(mt * 16 + kgrp * 4 + j) * BP + (nt - 4) * 16 + colL] =
                    (unsigned short)f2bf(siluf(m[nt][j]));
    }

    // ---- upd = m1@W2 + b2 ----
    f32x4 u[4];
    #pragma unroll
    for (int nt = 0; nt < 4; ++nt) {
        float b = mlp_b2_l[nt * 16 + colL];
        u[nt][0] = b; u[nt][1] = b; u[nt][2] = b; u[nt][3] = b;
    }
    #pragma unroll
    for (int kb = 0; kb < 4; ++kb) {
        short8 am = (kb < 2)
            ? *(const short8*)&Q[(mt * 16 + colL) * BP + kb * 32 + kgrp * 8]
            : *(const short8*)&S[(mt * 16 + colL) * BP + (kb - 2) * 32 + kgrp * 8];
        #pragma unroll
        for (int nt = 0; nt < 4; ++nt) {
            short8 bw = *(const short8*)&W2T_l[(nt * 16 + colL) * 128 + kb * 32 + kgrp * 8];
            u[nt] = MFMA16(am, bw, u[nt], 0, 0, 0);
        }
    }

    // ---- residual (from snapshot) + LayerNorm ----
    float y[4][4];
    float s1[4] = {0, 0, 0, 0}, s2[4] = {0, 0, 0, 0};
    #pragma unroll
    for (int j = 0; j < 4; ++j) {
        #pragma unroll
        for (int nt = 0; nt < 4; ++nt) {
            float v = xres[nt][j] + u[nt][j];
            y[nt][j] = v;
            s1[j] += v; s2[j] += v * v;
        }
    }
    #pragma unroll
    for (int off = 1; off < 16; off <<= 1) {
        #pragma unroll
        for (int j = 0; j < 4; ++j) {
            s1[j] += __shfl_xor(s1[j], off, 64);
            s2[j] += __shfl_xor(s2[j], off, 64);
        }
    }
    float gv[4], bv[4];
    #pragma unroll
    for (int nt = 0; nt < 4; ++nt) {
        gv[nt] = ln_g_l[nt * 16 + colL];
        bv[nt] = ln_b_l[nt * 16 + colL];
    }
    if constexpr (!FINAL) {
        // f8 byte tile inside the wave's own S band (2304 B); rows 80 B
        unsigned char* f8t = (unsigned char*)S + mt * 2304;
        #pragma unroll
        for (int j = 0; j < 4; ++j) {
            int lr = kgrp * 4 + j;          // local row 0..15
            float mu  = s1[j] * (1.0f / 64.0f);
            float var = s2[j] * (1.0f / 64.0f) - mu * mu;
            float rr  = rsqrtf(var + 1e-5f);
            #pragma unroll
            for (int nt = 0; nt < 4; ++nt) {
                float o = (y[nt][j] - mu) * rr * gv[nt] + bv[nt];
                P[(mt * 16 + lr) * BP + nt * 16 + colL] = (unsigned short)f2bf(o);
                f8t[lr * 80 + nt * 16 + colL] = (unsigned char)f2e5(o);
            }
        }
        // per-wave vectorized copy-out of own 16 rows
        #pragma unroll
        for (int i = 0; i < 2; ++i) {
            int t = i * 64 + lane;
            int row = mt * 16 + (t >> 3), q = t & 7;
            if (nb0 + row < N_NODES)
                *(uint4*)(featsbf + (size_t)(nb0 + row) * 64 + q * 8) =
                    *(const uint4*)&P[row * BP + q * 8];
        }
        {
            int lr = lane >> 2, q = lane & 3;
            int row = mt * 16 + lr;
            if (nb0 + row < N_NODES)
                *(uint4*)(featsf8 + (size_t)(nb0 + row) * 64 + q * 16) =
                    *(const uint4*)&f8t[lr * 80 + q * 16];
        }
    } else {
        // LN out -> P band (own rows; in-wave program order suffices)
        #pragma unroll
        for (int j = 0; j < 4; ++j) {
            float mu  = s1[j] * (1.0f / 64.0f);
            float var = s2[j] * (1.0f / 64.0f) - mu * mu;
            float rr  = rsqrtf(var + 1e-5f);
            #pragma unroll
            for (int nt = 0; nt < 4; ++nt) {
                float o = (y[nt][j] - mu) * rr * gv[nt] + bv[nt];
                P[(mt * 16 + kgrp * 4 + j) * BP + nt * 16 + colL] = (unsigned short)f2bf(o);
            }
        }

        // ---- h1 = silu(x @ Ro1 + b1) ----
        {
            f32x4 m[4];
            #pragma unroll
            for (int nt = 0; nt < 4; ++nt) {
                float b = ro_b1[nt * 16 + colL];
                m[nt][0] = b; m[nt][1] = b; m[nt][2] = b; m[nt][3] = b;
            }
            #pragma unroll
            for (int kb = 0; kb < 2; ++kb) {
                short8 ax = *(const short8*)&P[(mt * 16 + colL) * BP + kb * 32 + kgrp * 8];
                #pragma unroll
                for (int nt = 0; nt < 4; ++nt) {
                    short8 bw = *(const short8*)&Ro1T[(nt * 16 + colL) * 64 + kb * 32 + kgrp * 8];
                    m[nt] = MFMA16(ax, bw, m[nt], 0, 0, 0);
                }
            }
            #pragma unroll
            for (int nt = 0; nt < 4; ++nt)
                #pragma unroll
                for (int j = 0; j < 4; ++j)
                    Q[(mt * 16 + kgrp * 4 + j) * BP + nt * 16 + colL] =
                        (unsigned short)f2bf(siluf(m[nt][j]));
        }

        // ---- h2 = silu(h1 @ Ro2 + b2), 32 wide; e = h2 @ ro_w3 ----
        f32x4 uu[2];
        #pragma unroll
        for (int nt = 0; nt < 2; ++nt) {
            float b = ro_b2[nt * 16 + colL];
            uu[nt][0] = b; uu[nt][1] = b; uu[nt][2] = b; uu[nt][3] = b;
        }
        #pragma unroll
        for (int kb = 0; kb < 2; ++kb) {
            short8 am = *(const short8*)&Q[(mt * 16 + colL) * BP + kb * 32 + kgrp * 8];
            #pragma unroll
            for (int nt = 0; nt < 2; ++nt) {
                short8 bw = *(const short8*)&Ro2T[(nt * 16 + colL) * 64 + kb * 32 + kgrp * 8];
                uu[nt] = MFMA16(am, bw, uu[nt], 0, 0, 0);
            }
        }
        float w3[2];
        #pragma unroll
        for (int nt = 0; nt < 2; ++nt) w3[nt] = ro_w3[nt * 16 + colL];
        float part = 0.0f;
        #pragma unroll
        for (int j = 0; j < 4; ++j) {
            float c = siluf(uu[0][j]) * w3[0] + siluf(uu[1][j]) * w3[1];
            #pragma unroll
            for (int off = 1; off < 16; off <<= 1) c += __shfl_xor(c, off, 64);
            int node = nb0 + mt * 16 + kgrp * 4 + j;
            if (colL == 0 && node < N_NODES)
                part += c + ro_b3[0] + atomic_e[an[node]];
        }
        float* sred = (float*)S;
        __syncthreads();                    // all waves done reading S before alias
        sred[tid] = part;
        __syncthreads();
        for (int off = 128; off > 0; off >>= 1) {
            if (tid < off) sred[tid] += sred[tid + off];
            __syncthreads();
        }
        if (tid == 0) blockpart[blockIdx.x] = sred[0];
    }
}

__global__ void k_final(const float* __restrict__ blockpart, int nb, float* __restrict__ out) {
    __shared__ float s[256];
    float acc = 0.f;
    for (int i = threadIdx.x; i < nb; i += 256) acc += blockpart[i];
    s[threadIdx.x] = acc; __syncthreads();
    for (int off = 128; off > 0; off >>= 1) {
        if (threadIdx.x < off) s[threadIdx.x] += s[threadIdx.x + off];
        __syncthreads();
    }
    if (threadIdx.x == 0) out[0] = s[0];
}

// ---------------- launch ----------------

extern "C" void kernel_launch(void* const* d_in, const int* in_sizes, int n_in,
                              void* d_out, int out_size, void* d_ws, size_t ws_size,
                              hipStream_t stream) {
    const int*   an       = (const int*)  d_in[0];
    const float* pos      = (const float*)d_in[1];
    const int*   edge     = (const int*)  d_in[2];
    const float* widths   = (const float*)d_in[3];
    const float* embed    = (const float*)d_in[4];
    const float* rad_w1   = (const float*)d_in[5];
    const float* rad_b1   = (const float*)d_in[6];
    const float* rad_w2   = (const float*)d_in[7];
    const float* rad_b2   = (const float*)d_in[8];
    const float* self_w   = (const float*)d_in[9];
    const float* self_b   = (const float*)d_in[10];
    const float* proj_w   = (const float*)d_in[11];
    const float* proj_b   = (const float*)d_in[12];
    const float* mlp_w1   = (const float*)d_in[13];
    const float* mlp_b1   = (const float*)d_in[14];
    const float* mlp_w2   = (const float*)d_in[15];
    const float* mlp_b2   = (const float*)d_in[16];
    const float* ln_g     = (const float*)d_in[17];
    const float* ln_b     = (const float*)d_in[18];
    const float* ro_w1    = (const float*)d_in[19];
    const float* ro_b1    = (const float*)d_in[20];
    const float* ro_w2    = (const float*)d_in[21];
    const float* ro_b2    = (const float*)d_in[22];
    const float* ro_w3    = (const float*)d_in[23];
    const float* ro_b3    = (const float*)d_in[24];
    const float* atomic_e = (const float*)d_in[25];

    char* w = (char*)d_ws;
    auto alloc = [&](size_t bytes) { char* p = w; w += (bytes + 255) & ~(size_t)255; return p; };
    unsigned short* featsbf = (unsigned short*)alloc(sizeof(unsigned short) * (N_NODES + 64) * HDIM);
    unsigned char* featsf8  = (unsigned char*)alloc(sizeof(unsigned char) * (N_NODES + 64) * HDIM);
    unsigned short* aggbf   = (unsigned short*)alloc(sizeof(unsigned short) * (N_NODES + 64) * HDIM);
    unsigned short* lutH = (unsigned short*)alloc(sizeof(unsigned short) * NLAYER * TLUT * HDIM);
    float* W2s       = (float*)alloc(sizeof(float) * NLAYER * HDIM * HDIM);
    float* b2s       = (float*)alloc(sizeof(float) * NLAYER * HDIM);
    float* Wsp       = (float*)alloc(sizeof(float) * NLAYER * HDIM * HDIM);
    float* bsp       = (float*)alloc(sizeof(float) * NLAYER * HDIM);
    unsigned short* WspT = (unsigned short*)alloc(sizeof(unsigned short) * NLAYER * 4096);
    unsigned short* PbT  = (unsigned short*)alloc(sizeof(unsigned short) * NLAYER * 4096);
    unsigned short* W1T  = (unsigned short*)alloc(sizeof(unsigned short) * NLAYER * 8192);
    unsigned short* W2T  = (unsigned short*)alloc(sizeof(unsigned short) * NLAYER * 8192);
    unsigned short* Ro1T = (unsigned short*)alloc(sizeof(unsigned short) * 4096);
    unsigned short* Ro2T = (unsigned short*)alloc(sizeof(unsigned short) * 2048);
    unsigned int* erec = (unsigned int*)alloc(sizeof(unsigned int) * N_EDGES);
    unsigned int* rec4 = (unsigned int*)alloc(sizeof(unsigned int) * N_EDGES);
    unsigned char* bkt = (unsigned char*)alloc(sizeof(unsigned char) * N_EDGES);
    unsigned int* binned = (unsigned int*)alloc(sizeof(unsigned int) * (size_t)NBKT * BCAP);
    int*   btail     = (int*)  alloc(sizeof(int) * 256);
    int*   starts    = (int*)  alloc(sizeof(int) * (N_NODES + 1));
    float* blockpart = (float*)alloc(sizeof(float) * 1024);
    (void)ws_size; (void)in_sizes; (void)n_in; (void)out_size;

    const int* erow = edge;
    const int* ecol = edge + N_EDGES;

    hipMemsetAsync(btail, 0, sizeof(int) * 256, stream);
    k_init<<<NBLK_EMBED + (N_EDGES + 255) / 256, 256, 0, stream>>>(
        an, embed, featsbf, featsf8, erow, ecol, pos, rec4, bkt);
    k_binA<<<(N_EDGES + TILE - 1) / TILE, 256, 0, stream>>>(rec4, bkt, btail, binned);
    k_binB<<<NBKT, 256, 0, stream>>>(binned, btail, starts, erec);
    k_prep<<<(NLAYER * HDIM * HDIM + NLAYER * HDIM + 255) / 256, 256, 0, stream>>>(
        rad_w2, self_w, proj_w, rad_b2, self_b, proj_b, W2s, Wsp, b2s, bsp);
    k_wtr<<<(NLAYER * 24576 + 6144 + 255) / 256, 256, 0, stream>>>(
        Wsp, proj_w, mlp_w1, mlp_w2, ro_w1, ro_w2, WspT, PbT, W1T, W2T, Ro1T, Ro2T);
    k_lut<<<NLAYER * TLUT, 64, 0, stream>>>(widths, rad_w1, rad_b1, W2s, b2s, lutH);

    for (int l = 0; l < NLAYER; ++l) {
        k_agg<<<AGG_BLOCKS, 256, 0, stream>>>((const uint2*)featsf8,
                                              (const uint4*)(lutH + (size_t)l * TLUT * HDIM),
                                              starts, erec, (uint4*)aggbf);
        if (l < NLAYER - 1) {
            k_node<false><<<782, 256, 0, stream>>>(featsbf, featsf8, aggbf,
                WspT + (size_t)l * 4096, PbT + (size_t)l * 4096,
                W1T + (size_t)l * 8192, W2T + (size_t)l * 8192,
                bsp + l * HDIM, mlp_b1 + l * 2 * HDIM, mlp_b2 + l * HDIM,
                ln_g + l * HDIM, ln_b + l * HDIM,
                nullptr, nullptr, nullptr, nullptr, nullptr, nullptr, nullptr,
                nullptr, nullptr);
        } else {
            k_node<true><<<782, 256, 0, stream>>>(featsbf, featsf8, aggbf,
                WspT + (size_t)l * 4096, PbT + (size_t)l * 4096,
                W1T + (size_t)l * 8192, W2T + (size_t)l * 8192,
                bsp + l * HDIM, mlp_b1 + l * 2 * HDIM, mlp_b2 + l * HDIM,
                ln_g + l * HDIM, ln_b + l * HDIM,
                an, Ro1T, Ro2T, ro_b1, ro_b2, ro_w3, ro_b3, atomic_e, blockpart);
        }
    }

    k_final<<<1, 256, 0, stream>>>(blockpart, 782, (float*)d_out);
}

// Round 32
// 344.179 us; speedup vs baseline: 1.0188x; 1.0188x over previous
//
#include <hip/hip_runtime.h>
#include <hip/hip_fp16.h>
#include <math.h>

// Problem constants (from reference)
constexpr int N_NODES = 50000;
constexpr int N_EDGES = 1600000;
constexpr int HDIM    = 64;
constexpr int NLAYER  = 5;
constexpr int NBASIS  = 8;
constexpr int TLUT    = 128;           // radial LUT entries (7-bit index)
constexpr float CUT_R = 5.0f;
constexpr float PI_F  = 3.14159265358979f;

// binned scatter: buckets of 256 nodes (r >> 8)
constexpr int NBKT = 196;
constexpr int BCAP = 9216;             // mean 8192 + ~11 sigma
constexpr int TILE = 2048;
constexpr int NBLK_EMBED = 3125;       // (N_NODES*16)/256  (4 channels/thread)
constexpr int AGG_BLOCKS = 2048;       // 8 blocks/CU, grid-stride over nodes
constexpr int LP = 72;                 // LUT LDS row pitch in ushorts (144B, 16B-aligned)

typedef __attribute__((ext_vector_type(8))) short short8;   // 8 bf16 (4 VGPRs)
typedef __attribute__((ext_vector_type(4))) float f32x4;    // MFMA acc
#define MFMA16 __builtin_amdgcn_mfma_f32_16x16x32_bf16

__device__ __forceinline__ float siluf(float x) { return x / (1.0f + __expf(-x)); }

// round-to-nearest-even f32 -> bf16 bits
__device__ __forceinline__ unsigned int f2bf(float x) {
    unsigned int b = __float_as_uint(x);
    return (b + 0x7fffu + ((b >> 16) & 1u)) >> 16;
}
__device__ __forceinline__ float bf_lo(unsigned int u) { return __uint_as_float(u << 16); }

// f32 -> fp8 e5m2 (RTNE via fp16 truncation with rounding)
__device__ __forceinline__ unsigned int f2e5(float x) {
    unsigned short b = __half_as_ushort(__float2half(x));
    return ((unsigned int)b + 0x7Fu + ((b >> 8) & 1u)) >> 8;
}

// uint <-> __half2 bit casts
__device__ __forceinline__ __half2 u2h2(unsigned int u) {
    union { unsigned int u; __half2 h; } x; x.u = u; return x.h;
}
__device__ __forceinline__ unsigned int h2u(__half2 h) {
    union { __half2 h; unsigned int u; } x; x.h = h; return x.u;
}

// block-wide exclusive scan of 256 values: wave shuffle scans + LDS combine.
__device__ __forceinline__ int blockScan256Excl(int cv, int tid, int* wtot) {
    int v = cv;
    int lane = tid & 63;
    #pragma unroll
    for (int off = 1; off < 64; off <<= 1) {
        int t = __shfl_up(v, off, 64);
        if (lane >= off) v += t;
    }
    if (lane == 63) wtot[tid >> 6] = v;
    __syncthreads();
    int pre = 0;
    #pragma unroll
    for (int w = 0; w < 4; ++w)
        if (w < (tid >> 6)) pre += wtot[w];
    __syncthreads();
    return v + pre - cv;                 // exclusive
}

// ---------------- setup kernels ----------------

// fused: node embedding (vectorized, 4 ch/thread) + per-edge record precompute
__global__ void k_init(const int* __restrict__ an, const float* __restrict__ embed,
                       unsigned short* __restrict__ featsbf,
                       unsigned char* __restrict__ featsf8,
                       const int* __restrict__ row, const int* __restrict__ col,
                       const float* __restrict__ pos,
                       unsigned int* __restrict__ rec4, unsigned char* __restrict__ bkt) {
    int b = blockIdx.x;
    if (b < NBLK_EMBED) {
        int i = b * 256 + threadIdx.x;          // 0 .. N_NODES*16-1
        int node = i >> 4, h4 = (i & 15) << 2;
        float4 v = *(const float4*)&embed[an[node] * HDIM + h4];
        ushort4 ub;
        ub.x = (unsigned short)f2bf(v.x); ub.y = (unsigned short)f2bf(v.y);
        ub.z = (unsigned short)f2bf(v.z); ub.w = (unsigned short)f2bf(v.w);
        *(ushort4*)&featsbf[(size_t)node * 64 + h4] = ub;
        uchar4 uc;
        uc.x = (unsigned char)f2e5(v.x); uc.y = (unsigned char)f2e5(v.y);
        uc.z = (unsigned char)f2e5(v.z); uc.w = (unsigned char)f2e5(v.w);
        *(uchar4*)&featsf8[(size_t)node * 64 + h4] = uc;
    } else {
        int e = (b - NBLK_EMBED) * 256 + threadIdx.x;
        if (e >= N_EDGES) return;
        int r = row[e], c = col[e];
        float dx = pos[c * 3 + 0] - pos[r * 3 + 0];
        float dy = pos[c * 3 + 1] - pos[r * 3 + 1];
        float dz = pos[c * 3 + 2] - pos[r * 3 + 2];
        float len = sqrtf(dx * dx + dy * dy + dz * dz);
        float t = len * ((float)(TLUT - 1) / CUT_R);
        t = fminf(t, (float)(TLUT - 1));
        unsigned int nn = (unsigned int)(t + 0.5f);
        if (nn > TLUT - 1) nn = TLUT - 1;
        rec4[e] = ((unsigned int)c << 16) | (nn << 8) | ((unsigned int)r & 255u);
        bkt[e]  = (unsigned char)(r >> 8);
    }
}

// pass A: pure LDS sort of precomputed records into bucket runs
__global__ __launch_bounds__(256) void k_binA(const unsigned int* __restrict__ rec4,
                                              const unsigned char* __restrict__ bkt,
                                              int* __restrict__ btail,
                                              unsigned int* __restrict__ binned) {
    __shared__ unsigned int ent[TILE];
    __shared__ short bb[TILE];
    __shared__ unsigned int sorted[TILE];
    __shared__ short sortedB[TILE];
    __shared__ int cnt[256], cnt2[256], base[256], gbase[256];
    __shared__ int wtot[4];
    const int tid = threadIdx.x;
    const int t0  = blockIdx.x * TILE;
    const int nv  = min(TILE, N_EDGES - t0);

    cnt[tid] = 0;
    __syncthreads();

    #pragma unroll
    for (int i = 0; i < TILE / 256; ++i) {
        int idx = i * 256 + tid;
        if (idx < nv) {
            ent[idx] = rec4[t0 + idx];
            int b = bkt[t0 + idx];
            bb[idx] = (short)b;
            atomicAdd(&cnt[b], 1);
        }
    }
    __syncthreads();
    int cv = cnt[tid];
    int excl = blockScan256Excl(cv, tid, wtot);
    base[tid] = excl;
    if (tid < NBKT && cv > 0) gbase[tid] = atomicAdd(&btail[tid], cv);
    cnt2[tid] = excl;
    __syncthreads();
    #pragma unroll
    for (int i = 0; i < TILE / 256; ++i) {
        int idx = i * 256 + tid;
        if (idx < nv) {
            int b = bb[idx];
            int p = atomicAdd(&cnt2[b], 1);
            sorted[p]  = ent[idx];
            sortedB[p] = (short)b;
        }
    }
    __syncthreads();
    for (int s = tid; s < nv; s += 256) {
        int b = sortedB[s];
        binned[(size_t)b * BCAP + gbase[b] + (s - base[b])] = sorted[s];
    }
}

// pass B: one block per 256-node bucket. Inline prefix over btail -> LDS
// histogram -> wave scan -> starts -> scatter erec via LDS cursors.
__global__ __launch_bounds__(256) void k_binB(const unsigned int* __restrict__ binned,
                                              const int* __restrict__ btail,
                                              int* __restrict__ starts,
                                              unsigned int* __restrict__ erec) {
    __shared__ int hist[256];
    __shared__ int cur[256];
    __shared__ int red[256];
    __shared__ int wtot[4];
    const int b = blockIdx.x;
    const int node0 = b << 8;
    const int t = threadIdx.x;
    int part = 0;
    for (int i = t; i < b; i += 256) part += btail[i];
    red[t] = part;
    hist[t] = 0;
    __syncthreads();
    for (int off = 128; off > 0; off >>= 1) {
        if (t < off) red[t] += red[t + off];
        __syncthreads();
    }
    const int bb0 = red[0];
    const int cnt = btail[b];
    const unsigned int* src = binned + (size_t)b * BCAP;
    for (int s = t; s < cnt; s += 256)
        atomicAdd(&hist[src[s] & 255u], 1);
    __syncthreads();
    int h = hist[t];
    int excl = bb0 + blockScan256Excl(h, t, wtot);
    int n = node0 + t;
    if (n < N_NODES) starts[n] = excl;
    if (b == 0 && t == 0) starts[N_NODES] = N_EDGES;
    cur[t] = excl;
    __syncthreads();
    for (int s = t; s < cnt; s += 256) {
        unsigned int p = src[s];
        int pp = atomicAdd(&cur[p & 255u], 1);
        erec[pp] = p;
    }
}

// fused: W2s/Wsp + biases b2s/bsp
__global__ void k_prep(const float* __restrict__ rad_w2, const float* __restrict__ self_w,
                       const float* __restrict__ proj_w,
                       const float* __restrict__ rad_b2, const float* __restrict__ self_b,
                       const float* __restrict__ proj_b,
                       float* __restrict__ W2s, float* __restrict__ Wsp,
                       float* __restrict__ b2s, float* __restrict__ bsp) {
    int i = blockIdx.x * blockDim.x + threadIdx.x;
    if (i < NLAYER * HDIM * HDIM) {
        int l = i / (HDIM * HDIM); int rem = i % (HDIM * HDIM);
        int k = rem / HDIM; int h = rem % HDIM;
        const float* w = rad_w2 + ((size_t)l * HDIM + k) * (HDIM * 3) + h * 3;
        W2s[i] = w[0] + w[1] + w[2];
        const float* sw = self_w + ((size_t)l * HDIM + k) * HDIM;
        const float* pw = proj_w + (size_t)l * 2 * HDIM * HDIM;
        float acc = 0.f;
        for (int m = 0; m < HDIM; ++m) acc += sw[m] * pw[m * HDIM + h];
        Wsp[i] = acc;
    } else {
        int i2 = i - NLAYER * HDIM * HDIM;
        if (i2 >= NLAYER * HDIM) return;
        int l = i2 / HDIM, h = i2 % HDIM;
        const float* rb2 = rad_b2 + l * HDIM * 3 + h * 3;
        b2s[i2] = rb2[0] + rb2[1] + rb2[2];
        float acc = proj_b[l * HDIM + h];
        const float* pw = proj_w + (size_t)l * 2 * HDIM * HDIM;
        const float* sb = self_b + l * HDIM;
        for (int m = 0; m < HDIM; ++m) acc += sb[m] * pw[m * HDIM + h];
        bsp[i2] = acc;
    }
}

// fused: bf16 transposed weights + readout weights
__global__ void k_wtr(const float* __restrict__ Wsp, const float* __restrict__ proj_w,
                      const float* __restrict__ mlp_w1, const float* __restrict__ mlp_w2,
                      const float* __restrict__ ro_w1, const float* __restrict__ ro_w2,
                      unsigned short* __restrict__ WspT, unsigned short* __restrict__ PbT,
                      unsigned short* __restrict__ W1T, unsigned short* __restrict__ W2T,
                      unsigned short* __restrict__ Ro1T, unsigned short* __restrict__ Ro2T) {
    int i = blockIdx.x * blockDim.x + threadIdx.x;
    if (i < NLAYER * 24576) {
        int l = i / 24576, off = i % 24576;
        if (off < 4096) {
            int n = off >> 6, k = off & 63;
            WspT[(size_t)l * 4096 + off] = (unsigned short)f2bf(Wsp[(size_t)l * 4096 + k * 64 + n]);
        } else if (off < 8192) {
            int o = off - 4096; int n = o >> 6, k = o & 63;
            PbT[(size_t)l * 4096 + o] =
                (unsigned short)f2bf(proj_w[(size_t)l * 8192 + (64 + k) * 64 + n]);
        } else if (off < 16384) {
            int o = off - 8192; int n = o >> 6, k = o & 63;
            W1T[(size_t)l * 8192 + o] = (unsigned short)f2bf(mlp_w1[(size_t)l * 8192 + k * 128 + n]);
        } else {
            int o = off - 16384; int n = o >> 7, k = o & 127;
            W2T[(size_t)l * 8192 + o] = (unsigned short)f2bf(mlp_w2[(size_t)l * 8192 + k * 64 + n]);
        }
    } else {
        int i2 = i - NLAYER * 24576;
        if (i2 >= 6144) return;
        if (i2 < 4096) {
            int n = i2 >> 6, k = i2 & 63;
            Ro1T[i2] = (unsigned short)f2bf(ro_w1[k * 64 + n]);
        } else {
            int o = i2 - 4096; int n = o >> 6, k = o & 63;
            Ro2T[o] = (unsigned short)f2bf(ro_w2[k * 32 + n]);
        }
    }
}

// radial LUT -> fp16 directly, channel positions pair-permuted for hfma2:
// within each 8-channel group, memory order is ch {0,2,1,3,4,6,5,7}.
__global__ void k_lut(const float* __restrict__ widths, const float* __restrict__ rad_w1,
                      const float* __restrict__ rad_b1, const float* __restrict__ W2s,
                      const float* __restrict__ b2s, unsigned short* __restrict__ lutH) {
    int bid = blockIdx.x;                 // l*TLUT + t
    int l = bid / TLUT, t = bid % TLUT;
    int h = threadIdx.x;                  // 64 threads
    __shared__ float h1s[HDIM];
    float len = (float)t * (CUT_R / (float)(TLUT - 1));
    float cut = 0.0f;
    if (len < CUT_R) cut = 0.5f * (cosf(len * (PI_F / CUT_R)) + 1.0f);
    float acc = rad_b1[l * HDIM + h];
    for (int b = 0; b < NBASIS; ++b) {
        float wb = fmaxf(widths[b], 0.1f);
        float center = (float)b * (CUT_R / (float)(NBASIS - 1));
        float d = (len - center) / wb;
        float rbf = __expf(-0.5f * d * d) * cut;
        acc += rbf * rad_w1[(l * NBASIS + b) * HDIM + h];
    }
    h1s[h] = siluf(acc);
    __syncthreads();
    float o = b2s[l * HDIM + h];
    const float* w2 = W2s + (size_t)l * HDIM * HDIM;
    for (int k = 0; k < HDIM; ++k) o += h1s[k] * w2[k * HDIM + h];
    int m = h & 7;
    int pos = (h & ~7) | (m & 4) | ((m & 1) << 1) | ((m >> 1) & 1);
    lutH[(size_t)bid * HDIM + pos] = __half_as_ushort(__float2half(o));
}

// ---------------- per-layer kernels ----------------

// grid-stride, 8 blocks/CU. LUT staged to LDS (144B row pitch) -> per-edge LUT
// reads hit the LDS pipe, leaving L1 entirely to the random feats gather.
__global__ __launch_bounds__(256) void k_agg(const uint2* __restrict__ featsf8_2,
                                             const uint4* __restrict__ lutH4_l,
                                             const int* __restrict__ starts,
                                             const unsigned int* __restrict__ erec,
                                             uint4* __restrict__ aggbf4) {
    __shared__ unsigned short lutS[TLUT * LP];     // 18432 B
    const int tid  = threadIdx.x;
    const int lane = tid & 63;
    const int slot = lane >> 3;    // 0..7
    const int j    = lane & 7;     // channel octet

    // stage LUT: 128 rows x 8 uint4, coalesced
    #pragma unroll
    for (int i = 0; i < 4; ++i) {
        int g = i * 256 + tid;     // 0..1023
        int row = g >> 3, q = g & 7;
        *(uint4*)&lutS[row * LP + q * 8] = lutH4_l[g];
    }
    __syncthreads();

    for (int wid = blockIdx.x * 4 + (tid >> 6); wid < N_NODES; wid += AGG_BLOCKS * 4) {
        int e0 = starts[wid], e1 = starts[wid + 1];
        __half2 a02 = u2h2(0u), a13 = u2h2(0u), a46 = u2h2(0u), a57 = u2h2(0u);
        #pragma unroll 2
        for (int e = e0 + slot; e < e1; e += 8) {
            unsigned int rec = erec[e];
            int c  = rec >> 16;
            int i0 = (rec >> 8) & 255;
            uint4 qw = *(const uint4*)&lutS[i0 * LP + j * 8];
            uint2 fb = featsf8_2[(size_t)c * 8 + j];
            a02 = __hfma2(u2h2((fb.x << 8) & 0xFF00FF00u), u2h2(qw.x), a02);
            a13 = __hfma2(u2h2(fb.x & 0xFF00FF00u),        u2h2(qw.y), a13);
            a46 = __hfma2(u2h2((fb.y << 8) & 0xFF00FF00u), u2h2(qw.z), a46);
            a57 = __hfma2(u2h2(fb.y & 0xFF00FF00u),        u2h2(qw.w), a57);
        }
        #pragma unroll
        for (int off = 8; off < 64; off <<= 1) {
            a02 = __hadd2(a02, u2h2((unsigned int)__shfl_xor((int)h2u(a02), off, 64)));
            a13 = __hadd2(a13, u2h2((unsigned int)__shfl_xor((int)h2u(a13), off, 64)));
            a46 = __hadd2(a46, u2h2((unsigned int)__shfl_xor((int)h2u(a46), off, 64)));
            a57 = __hadd2(a57, u2h2((unsigned int)__shfl_xor((int)h2u(a57), off, 64)));
        }
        if (slot == 0) {
            float c0 = __low2float(a02), c2 = __high2float(a02);
            float c1 = __low2float(a13), c3 = __high2float(a13);
            float c4 = __low2float(a46), c6 = __high2float(a46);
            float c5 = __low2float(a57), c7 = __high2float(a57);
            uint4 o;
            o.x = f2bf(c0) | (f2bf(c1) << 16);
            o.y = f2bf(c2) | (f2bf(c3) << 16);
            o.z = f2bf(c4) | (f2bf(c5) << 16);
            o.w = f2bf(c6) | (f2bf(c7) << 16);
            aggbf4[(size_t)wid * 8 + j] = o;
        }
    }
}

// k_node (MFMA): 64 nodes/block, 4 waves, BARRIER-FREE in the layer path.
// Every phase touches only the calling wave's 16-row LDS band (rows
// mt*16..mt*16+15 of P/Q/S); staging/copy-out are per-wave; the f8 byte tile
// lives inside the wave's own S band (offset mt*2304, 80B rows). Intra-wave
// LDS dependencies are program-ordered, so no __syncthreads is needed.
// FINAL keeps one barrier before the cross-wave sred reduction (aliases S).
constexpr int BP = 72;                     // bf16 LDS row pitch (144B, 16B-aligned)
template <bool FINAL>
__global__ __launch_bounds__(256) void k_node(
        unsigned short* __restrict__ featsbf,
        unsigned char* __restrict__ featsf8,
        const unsigned short* __restrict__ aggbf,
        const unsigned short* __restrict__ WspT_l, const unsigned short* __restrict__ PbT_l,
        const unsigned short* __restrict__ W1T_l, const unsigned short* __restrict__ W2T_l,
        const float* __restrict__ bsp_l,
        const float* __restrict__ mlp_b1_l, const float* __restrict__ mlp_b2_l,
        const float* __restrict__ ln_g_l, const float* __restrict__ ln_b_l,
        const int* __restrict__ an,
        const unsigned short* __restrict__ Ro1T, const unsigned short* __restrict__ Ro2T,
        const float* __restrict__ ro_b1, const float* __restrict__ ro_b2,
        const float* __restrict__ ro_w3, const float* __restrict__ ro_b3,
        const float* __restrict__ atomic_e, float* __restrict__ blockpart) {
    __shared__ unsigned short P[64 * BP];   // x -> conv -> LN out
    __shared__ unsigned short Q[64 * BP];   // a -> m1_lo -> (FINAL: h1)
    __shared__ unsigned short S[64 * BP];   // m1_hi -> f8 band tile / sred
    const int tid  = threadIdx.x;
    const int lane = tid & 63;
    const int wib  = tid >> 6;
    const int mt   = __builtin_amdgcn_readfirstlane(wib);
    const int nb0  = blockIdx.x * 64;
    const int colL = lane & 15;
    const int kgrp = lane >> 4;

    // per-wave staging: wave mt stages its own rows [16mt,16mt+16), 2 uint4/lane
    {
        const uint4* gP = (const uint4*)(featsbf + (size_t)nb0 * 64);
        const uint4* gQ = (const uint4*)(aggbf  + (size_t)nb0 * 64);
        #pragma unroll
        for (int i = 0; i < 2; ++i) {
            int t = i * 64 + lane;          // 0..127 within wave
            int row = mt * 16 + (t >> 3), q = t & 7;
            *(uint4*)&P[row * BP + q * 8] = gP[row * 8 + q];
            *(uint4*)&Q[row * BP + q * 8] = gQ[row * 8 + q];
        }
    }

    // snapshot residual x (bf16 from LDS) before P is overwritten by conv
    float xres[4][4];                       // [nt][j]
    #pragma unroll
    for (int j = 0; j < 4; ++j)
        #pragma unroll
        for (int nt = 0; nt < 4; ++nt)
            xres[nt][j] = bf_lo(P[(mt * 16 + kgrp * 4 + j) * BP + nt * 16 + colL]);

    // ---- conv = x@Wsp + a@Pb + bsp ----
    f32x4 acc[4];
    #pragma unroll
    for (int nt = 0; nt < 4; ++nt) {
        float b = bsp_l[nt * 16 + colL];
        acc[nt][0] = b; acc[nt][1] = b; acc[nt][2] = b; acc[nt][3] = b;
    }
    #pragma unroll
    for (int kb = 0; kb < 2; ++kb) {
        short8 ax = *(const short8*)&P[(mt * 16 + colL) * BP + kb * 32 + kgrp * 8];
        short8 aa = *(const short8*)&Q[(mt * 16 + colL) * BP + kb * 32 + kgrp * 8];
        #pragma unroll
        for (int nt = 0; nt < 4; ++nt) {
            short8 bw = *(const short8*)&WspT_l[(nt * 16 + colL) * 64 + kb * 32 + kgrp * 8];
            acc[nt] = MFMA16(ax, bw, acc[nt], 0, 0, 0);
            short8 bp = *(const short8*)&PbT_l[(nt * 16 + colL) * 64 + kb * 32 + kgrp * 8];
            acc[nt] = MFMA16(aa, bp, acc[nt], 0, 0, 0);
        }
    }
    #pragma unroll
    for (int nt = 0; nt < 4; ++nt)
        #pragma unroll
        for (int j = 0; j < 4; ++j)
            P[(mt * 16 + kgrp * 4 + j) * BP + nt * 16 + colL] = (unsigned short)f2bf(acc[nt][j]);

    // ---- m1 = silu(conv@W1 + b1), 128 wide ----
    {
        f32x4 m[8];
        #pragma unroll
        for (int nt = 0; nt < 8; ++nt) {
            float b = mlp_b1_l[nt * 16 + colL];
            m[nt][0] = b; m[nt][1] = b; m[nt][2] = b; m[nt][3] = b;
        }
        #pragma unroll
        for (int kb = 0; kb < 2; ++kb) {
            short8 ac = *(const short8*)&P[(mt * 16 + colL) * BP + kb * 32 + kgrp * 8];
            #pragma unroll
            for (int nt = 0; nt < 8; ++nt) {
                short8 bw = *(const short8*)&W1T_l[(nt * 16 + colL) * 64 + kb * 32 + kgrp * 8];
                m[nt] = MFMA16(ac, bw, m[nt], 0, 0, 0);
            }
        }
        #pragma unroll
        for (int nt = 0; nt < 4; ++nt)
            #pragma unroll
            for (int j = 0; j < 4; ++j)
                Q[(mt * 16 + kgrp * 4 + j) * BP + nt * 16 + colL] =
                    (unsigned short)f2bf(siluf(m[nt][j]));
        #pragma unroll
        for (int nt = 4; nt < 8; ++nt)
            #pragma unroll
            for (int j = 0; j < 4; ++j)
                S[(mt * 16 + kgrp * 4 + j) * BP + (nt - 4) * 16 + colL] =
                    (unsigned short)f2bf(siluf(m[nt][j]));
    }

    // ---- upd = m1@W2 + b2 ----
    f32x4 u[4];
    #pragma unroll
    for (int nt = 0; nt < 4; ++nt) {
        float b = mlp_b2_l[nt * 16 + colL];
        u[nt][0] = b; u[nt][1] = b; u[nt][2] = b; u[nt][3] = b;
    }
    #pragma unroll
    for (int kb = 0; kb < 4; ++kb) {
        short8 am = (kb < 2)
            ? *(const short8*)&Q[(mt * 16 + colL) * BP + kb * 32 + kgrp * 8]
            : *(const short8*)&S[(mt * 16 + colL) * BP + (kb - 2) * 32 + kgrp * 8];
        #pragma unroll
        for (int nt = 0; nt < 4; ++nt) {
            short8 bw = *(const short8*)&W2T_l[(nt * 16 + colL) * 128 + kb * 32 + kgrp * 8];
            u[nt] = MFMA16(am, bw, u[nt], 0, 0, 0);
        }
    }

    // ---- residual (from snapshot) + LayerNorm ----
    float y[4][4];
    float s1[4] = {0, 0, 0, 0}, s2[4] = {0, 0, 0, 0};
    #pragma unroll
    for (int j = 0; j < 4; ++j) {
        #pragma unroll
        for (int nt = 0; nt < 4; ++nt) {
            float v = xres[nt][j] + u[nt][j];
            y[nt][j] = v;
            s1[j] += v; s2[j] += v * v;
        }
    }
    #pragma unroll
    for (int off = 1; off < 16; off <<= 1) {
        #pragma unroll
        for (int j = 0; j < 4; ++j) {
            s1[j] += __shfl_xor(s1[j], off, 64);
            s2[j] += __shfl_xor(s2[j], off, 64);
        }
    }
    float gv[4], bv[4];
    #pragma unroll
    for (int nt = 0; nt < 4; ++nt) {
        gv[nt] = ln_g_l[nt * 16 + colL];
        bv[nt] = ln_b_l[nt * 16 + colL];
    }
    if constexpr (!FINAL) {
        // f8 byte tile inside the wave's own S band (2304 B); rows 80 B
        unsigned char* f8t = (unsigned char*)S + mt * 2304;
        #pragma unroll
        for (int j = 0; j < 4; ++j) {
            int lr = kgrp * 4 + j;          // local row 0..15
            float mu  = s1[j] * (1.0f / 64.0f);
            float var = s2[j] * (1.0f / 64.0f) - mu * mu;
            float rr  = rsqrtf(var + 1e-5f);
            #pragma unroll
            for (int nt = 0; nt < 4; ++nt) {
                float o = (y[nt][j] - mu) * rr * gv[nt] + bv[nt];
                P[(mt * 16 + lr) * BP + nt * 16 + colL] = (unsigned short)f2bf(o);
                f8t[lr * 80 + nt * 16 + colL] = (unsigned char)f2e5(o);
            }
        }
        // per-wave vectorized copy-out of own 16 rows
        #pragma unroll
        for (int i = 0; i < 2; ++i) {
            int t = i * 64 + lane;
            int row = mt * 16 + (t >> 3), q = t & 7;
            if (nb0 + row < N_NODES)
                *(uint4*)(featsbf + (size_t)(nb0 + row) * 64 + q * 8) =
                    *(const uint4*)&P[row * BP + q * 8];
        }
        {
            int lr = lane >> 2, q = lane & 3;
            int row = mt * 16 + lr;
            if (nb0 + row < N_NODES)
                *(uint4*)(featsf8 + (size_t)(nb0 + row) * 64 + q * 16) =
                    *(const uint4*)&f8t[lr * 80 + q * 16];
        }
    } else {
        // LN out -> P band (own rows; in-wave program order suffices)
        #pragma unroll
        for (int j = 0; j < 4; ++j) {
            float mu  = s1[j] * (1.0f / 64.0f);
            float var = s2[j] * (1.0f / 64.0f) - mu * mu;
            float rr  = rsqrtf(var + 1e-5f);
            #pragma unroll
            for (int nt = 0; nt < 4; ++nt) {
                float o = (y[nt][j] - mu) * rr * gv[nt] + bv[nt];
                P[(mt * 16 + kgrp * 4 + j) * BP + nt * 16 + colL] = (unsigned short)f2bf(o);
            }
        }

        // ---- h1 = silu(x @ Ro1 + b1) ----
        {
            f32x4 m[4];
            #pragma unroll
            for (int nt = 0; nt < 4; ++nt) {
                float b = ro_b1[nt * 16 + colL];
                m[nt][0] = b; m[nt][1] = b; m[nt][2] = b; m[nt][3] = b;
            }
            #pragma unroll
            for (int kb = 0; kb < 2; ++kb) {
                short8 ax = *(const short8*)&P[(mt * 16 + colL) * BP + kb * 32 + kgrp * 8];
                #pragma unroll
                for (int nt = 0; nt < 4; ++nt) {
                    short8 bw = *(const short8*)&Ro1T[(nt * 16 + colL) * 64 + kb * 32 + kgrp * 8];
                    m[nt] = MFMA16(ax, bw, m[nt], 0, 0, 0);
                }
            }
            #pragma unroll
            for (int nt = 0; nt < 4; ++nt)
                #pragma unroll
                for (int j = 0; j < 4; ++j)
                    Q[(mt * 16 + kgrp * 4 + j) * BP + nt * 16 + colL] =
                        (unsigned short)f2bf(siluf(m[nt][j]));
        }

        // ---- h2 = silu(h1 @ Ro2 + b2), 32 wide; e = h2 @ ro_w3 ----
        f32x4 uu[2];
        #pragma unroll
        for (int nt = 0; nt < 2; ++nt) {
            float b = ro_b2[nt * 16 + colL];
            uu[nt][0] = b; uu[nt][1] = b; uu[nt][2] = b; uu[nt][3] = b;
        }
        #pragma unroll
        for (int kb = 0; kb < 2; ++kb) {
            short8 am = *(const short8*)&Q[(mt * 16 + colL) * BP + kb * 32 + kgrp * 8];
            #pragma unroll
            for (int nt = 0; nt < 2; ++nt) {
                short8 bw = *(const short8*)&Ro2T[(nt * 16 + colL) * 64 + kb * 32 + kgrp * 8];
                uu[nt] = MFMA16(am, bw, uu[nt], 0, 0, 0);
            }
        }
        float w3[2];
        #pragma unroll
        for (int nt = 0; nt < 2; ++nt) w3[nt] = ro_w3[nt * 16 + colL];
        float part = 0.0f;
        #pragma unroll
        for (int j = 0; j < 4; ++j) {
            float c = siluf(uu[0][j]) * w3[0] + siluf(uu[1][j]) * w3[1];
            #pragma unroll
            for (int off = 1; off < 16; off <<= 1) c += __shfl_xor(c, off, 64);
            int node = nb0 + mt * 16 + kgrp * 4 + j;
            if (colL == 0 && node < N_NODES)
                part += c + ro_b3[0] + atomic_e[an[node]];
        }
        float* sred = (float*)S;
        __syncthreads();                    // all waves done reading S before alias
        sred[tid] = part;
        __syncthreads();
        for (int off = 128; off > 0; off >>= 1) {
            if (tid < off) sred[tid] += sred[tid + off];
            __syncthreads();
        }
        if (tid == 0) blockpart[blockIdx.x] = sred[0];
    }
}

__global__ void k_final(const float* __restrict__ blockpart, int nb, float* __restrict__ out) {
    __shared__ float s[256];
    float acc = 0.f;
    for (int i = threadIdx.x; i < nb; i += 256) acc += blockpart[i];
    s[threadIdx.x] = acc; __syncthreads();
    for (int off = 128; off > 0; off >>= 1) {
        if (threadIdx.x < off) s[threadIdx.x] += s[threadIdx.x + off];
        __syncthreads();
    }
    if (threadIdx.x == 0) out[0] = s[0];
}

// ---------------- launch ----------------

extern "C" void kernel_launch(void* const* d_in, const int* in_sizes, int n_in,
                              void* d_out, int out_size, void* d_ws, size_t ws_size,
                              hipStream_t stream) {
    const int*   an       = (const int*)  d_in[0];
    const float* pos      = (const float*)d_in[1];
    const int*   edge     = (const int*)  d_in[2];
    const float* widths   = (const float*)d_in[3];
    const float* embed    = (const float*)d_in[4];
    const float* rad_w1   = (const float*)d_in[5];
    const float* rad_b1   = (const float*)d_in[6];
    const float* rad_w2   = (const float*)d_in[7];
    const float* rad_b2   = (const float*)d_in[8];
    const float* self_w   = (const float*)d_in[9];
    const float* self_b   = (const float*)d_in[10];
    const float* proj_w   = (const float*)d_in[11];
    const float* proj_b   = (const float*)d_in[12];
    const float* mlp_w1   = (const float*)d_in[13];
    const float* mlp_b1   = (const float*)d_in[14];
    const float* mlp_w2   = (const float*)d_in[15];
    const float* mlp_b2   = (const float*)d_in[16];
    const float* ln_g     = (const float*)d_in[17];
    const float* ln_b     = (const float*)d_in[18];
    const float* ro_w1    = (const float*)d_in[19];
    const float* ro_b1    = (const float*)d_in[20];
    const float* ro_w2    = (const float*)d_in[21];
    const float* ro_b2    = (const float*)d_in[22];
    const float* ro_w3    = (const float*)d_in[23];
    const float* ro_b3    = (const float*)d_in[24];
    const float* atomic_e = (const float*)d_in[25];

    char* w = (char*)d_ws;
    auto alloc = [&](size_t bytes) { char* p = w; w += (bytes + 255) & ~(size_t)255; return p; };
    unsigned short* featsbf = (unsigned short*)alloc(sizeof(unsigned short) * (N_NODES + 64) * HDIM);
    unsigned char* featsf8  = (unsigned char*)alloc(sizeof(unsigned char) * (N_NODES + 64) * HDIM);
    unsigned short* aggbf   = (unsigned short*)alloc(sizeof(unsigned short) * (N_NODES + 64) * HDIM);
    unsigned short* lutH = (unsigned short*)alloc(sizeof(unsigned short) * NLAYER * TLUT * HDIM);
    float* W2s       = (float*)alloc(sizeof(float) * NLAYER * HDIM * HDIM);
    float* b2s       = (float*)alloc(sizeof(float) * NLAYER * HDIM);
    float* Wsp       = (float*)alloc(sizeof(float) * NLAYER * HDIM * HDIM);
    float* bsp       = (float*)alloc(sizeof(float) * NLAYER * HDIM);
    unsigned short* WspT = (unsigned short*)alloc(sizeof(unsigned short) * NLAYER * 4096);
    unsigned short* PbT  = (unsigned short*)alloc(sizeof(unsigned short) * NLAYER * 4096);
    unsigned short* W1T  = (unsigned short*)alloc(sizeof(unsigned short) * NLAYER * 8192);
    unsigned short* W2T  = (unsigned short*)alloc(sizeof(unsigned short) * NLAYER * 8192);
    unsigned short* Ro1T = (unsigned short*)alloc(sizeof(unsigned short) * 4096);
    unsigned short* Ro2T = (unsigned short*)alloc(sizeof(unsigned short) * 2048);
    unsigned int* erec = (unsigned int*)alloc(sizeof(unsigned int) * N_EDGES);
    unsigned int* rec4 = (unsigned int*)alloc(sizeof(unsigned int) * N_EDGES);
    unsigned char* bkt = (unsigned char*)alloc(sizeof(unsigned char) * N_EDGES);
    unsigned int* binned = (unsigned int*)alloc(sizeof(unsigned int) * (size_t)NBKT * BCAP);
    int*   btail     = (int*)  alloc(sizeof(int) * 256);
    int*   starts    = (int*)  alloc(sizeof(int) * (N_NODES + 1));
    float* blockpart = (float*)alloc(sizeof(float) * 1024);
    (void)ws_size; (void)in_sizes; (void)n_in; (void)out_size;

    const int* erow = edge;
    const int* ecol = edge + N_EDGES;

    hipMemsetAsync(btail, 0, sizeof(int) * 256, stream);
    k_init<<<NBLK_EMBED + (N_EDGES + 255) / 256, 256, 0, stream>>>(
        an, embed, featsbf, featsf8, erow, ecol, pos, rec4, bkt);
    k_binA<<<(N_EDGES + TILE - 1) / TILE, 256, 0, stream>>>(rec4, bkt, btail, binned);
    k_binB<<<NBKT, 256, 0, stream>>>(binned, btail, starts, erec);
    k_prep<<<(NLAYER * HDIM * HDIM + NLAYER * HDIM + 255) / 256, 256, 0, stream>>>(
        rad_w2, self_w, proj_w, rad_b2, self_b, proj_b, W2s, Wsp, b2s, bsp);
    k_wtr<<<(NLAYER * 24576 + 6144 + 255) / 256, 256, 0, stream>>>(
        Wsp, proj_w, mlp_w1, mlp_w2, ro_w1, ro_w2, WspT, PbT, W1T, W2T, Ro1T, Ro2T);
    k_lut<<<NLAYER * TLUT, 64, 0, stream>>>(widths, rad_w1, rad_b1, W2s, b2s, lutH);

    for (int l = 0; l < NLAYER; ++l) {
        k_agg<<<AGG_BLOCKS, 256, 0, stream>>>((const uint2*)featsf8,
                                              (const uint4*)(lutH + (size_t)l * TLUT * HDIM),
                                              starts, erec, (uint4*)aggbf);
        if (l < NLAYER - 1) {
            k_node<false><<<782, 256, 0, stream>>>(featsbf, featsf8, aggbf,
                WspT + (size_t)l * 4096, PbT + (size_t)l * 4096,
                W1T + (size_t)l * 8192, W2T + (size_t)l * 8192,
                bsp + l * HDIM, mlp_b1 + l * 2 * HDIM, mlp_b2 + l * HDIM,
                ln_g + l * HDIM, ln_b + l * HDIM,
                nullptr, nullptr, nullptr, nullptr, nullptr, nullptr, nullptr,
                nullptr, nullptr);
        } else {
            k_node<true><<<782, 256, 0, stream>>>(featsbf, featsf8, aggbf,
                WspT + (size_t)l * 4096, PbT + (size_t)l * 4096,
                W1T + (size_t)l * 8192, W2T + (size_t)l * 8192,
                bsp + l * HDIM, mlp_b1 + l * 2 * HDIM, mlp_b2 + l * HDIM,
                ln_g + l * HDIM, ln_b + l * HDIM,
                an, Ro1T, Ro2T, ro_b1, ro_b2, ro_w3, ro_b3, atomic_e, blockpart);
        }
    }

    k_final<<<1, 256, 0, stream>>>(blockpart, 782, (float*)d_out);
}